// Round 2
// baseline (363.138 us; speedup 1.0000x reference)
//
#include <hip/hip_runtime.h>
#include <hip/hip_bf16.h>
#include <math.h>

typedef __hip_bfloat16 bf16;
typedef __attribute__((ext_vector_type(8))) short s8v;   // 8 bf16 (4 VGPRs)
typedef __attribute__((ext_vector_type(4))) float f4v;

#define B_   16
#define T_   1024
#define C_   512
#define M_   (B_*T_)      // 16384
#define NW_  4
#define KWIN 25

__device__ __forceinline__ float b2f(bf16 v){ return __bfloat162float(v); }
__device__ __forceinline__ bf16  f2b(float v){ return __float2bfloat16(v); }

// ---------------------------------------------------------------- K0: repack f32 weights -> transposed bf16 panels
__global__ __launch_bounds__(256) void repack_kernel(
    const float* __restrict__ cheby,  // [C][C][4]  (c,o,d)
    const float* __restrict__ wav,    // [NW][C][C] (w,c,o)
    const float* __restrict__ ampw,   // [C][C]     (c,o)
    bf16* __restrict__ CCT,           // [512][2048] : CCT[o][c*4+d]
    bf16* __restrict__ WWT,           // [512][2048] : WWT[o][w*512+c]
    bf16* __restrict__ AWT)           // [512][512]  : AWT[o][c]
{
    int id = blockIdx.x * 256 + threadIdx.x;
    if (id < 512 * 2048) {
        int o = id >> 11, k = id & 2047;
        int c = k >> 2, d = k & 3;
        CCT[id] = f2b(cheby[c * 2048 + o * 4 + d]);
        int w = k >> 9, c2 = k & 511;
        WWT[id] = f2b(wav[(w * 512 + c2) * 512 + o]);
    }
    if (id < 512 * 512) {
        int o = id >> 9, c = id & 511;
        AWT[id] = f2b(ampw[c * 512 + o]);
    }
}

// ---------------------------------------------------------------- K1: causal MA + dwconv3 x3 + pools, streaming over t
__global__ __launch_bounds__(256) void decomp_kernel(
    const float* __restrict__ x,
    const float* __restrict__ tcw, const float* __restrict__ tcb,
    const float* __restrict__ scw, const float* __restrict__ scb,
    const float* __restrict__ lcw, const float* __restrict__ lcb,
    bf16* __restrict__ xt,        // tanh(trend_ctx)  [M][C]
    bf16* __restrict__ sctx,      // spike_ctx        [M][C]
    float* __restrict__ slope_part,  // [8][B][C]
    float* __restrict__ value_part)  // [8][B][C]
{
    const int c     = blockIdx.x * 256 + threadIdx.x;  // gridDim.x = 2
    const int chunk = blockIdx.y;                      // 8 chunks of 128
    const int b     = blockIdx.z;
    const int t0    = chunk * 128;
    const float* xb = x + (size_t)b * T_ * C_ + c;

    auto X = [&](int i) -> float {
        i = i < 0 ? 0 : (i > T_ - 1 ? T_ - 1 : i);
        return xb[(size_t)i * C_];
    };

    const float w0t = tcw[c*3+0], w1t = tcw[c*3+1], w2t = tcw[c*3+2], bt0 = tcb[c];
    const float w0s = scw[c*3+0], w1s = scw[c*3+1], w2s = scw[c*3+2], bs0 = scb[c];
    const float w0l = lcw[c*3+0], w1l = lcw[c*3+1], w2l = lcw[c*3+2], bl0 = lcb[c];

    // init sliding window sum at j0 = max(t0-1, 0); window [j-24, j], K=25
    int j0 = (t0 > 0) ? (t0 - 1) : 0;
    float S = 0.f;
    #pragma unroll 1
    for (int i = j0 - (KWIN - 1); i <= j0; ++i) S += X(i);
    float trm = S * (1.f / KWIN), tr0;
    if (t0 > 0) { S += X(t0) - X(t0 - KWIN); tr0 = S * (1.f / KWIN); }
    else        { tr0 = trm; }
    float xm = X(t0 - 1), x0 = X(t0);

    float slopeAcc = 0.f, valAcc = 0.f;
    #pragma unroll 1
    for (int t = t0; t < t0 + 128; ++t) {
        float trp, xp;
        int tn = t + 1;
        if (tn <= T_ - 1) { S += X(tn) - X(tn - KWIN); trp = S * (1.f / KWIN); xp = X(tn); }
        else              { trp = tr0; xp = x0; }   // replicate pad at right edge

        float tctx  = w0t * trm + w1t * tr0 + w2t * trp + bt0;
        float sm = xm - trm, s0 = x0 - tr0, sp = xp - trp;
        float sctxv = w0s * sm + w1s * s0 + w2s * sp + bs0;
        float slp   = w0l * trm + w1l * tr0 + w2l * trp + bl0;
        slopeAcc += slp;
        valAcc   += tr0;

        size_t oidx = ((size_t)b * T_ + t) * C_ + c;
        xt[oidx]   = f2b(tanhf(tctx));
        sctx[oidx] = f2b(sctxv);

        trm = tr0; tr0 = trp; xm = x0; x0 = xp;
    }
    int pidx = (chunk * B_ + b) * C_ + c;
    slope_part[pidx] = slopeAcc;
    value_part[pidx] = valAcc;
}

// ---------------------------------------------------------------- K2: hypernetwork -> dyn_a, dyn_b
__global__ __launch_bounds__(256) void hyper_kernel(
    const float* __restrict__ slope_part, const float* __restrict__ value_part,
    const float* __restrict__ w1, const float* __restrict__ b1,
    const float* __restrict__ w2, const float* __restrict__ b2,
    float* __restrict__ dyn_a, float* __restrict__ dyn_b)
{
    __shared__ float pc[1024];
    __shared__ float hb[512];
    __shared__ float pp[8];
    const int b = blockIdx.x, tid = threadIdx.x;

    for (int j = tid; j < 1024; j += 256) {
        int cc = j & 511;
        const float* src = (j < 512) ? slope_part : value_part;
        float s = 0.f;
        #pragma unroll
        for (int ch = 0; ch < 8; ++ch) s += src[(ch * B_ + b) * C_ + cc];
        pc[j] = s * (1.f / T_);
    }
    __syncthreads();
    for (int o = tid; o < 512; o += 256) {
        float acc = b1[o];
        #pragma unroll 4
        for (int j = 0; j < 1024; ++j) acc += pc[j] * w1[j * 512 + o];
        hb[o] = acc / (1.f + expf(-acc));   // silu
    }
    __syncthreads();
    if (tid < 8) {
        float acc = b2[tid];
        for (int o = 0; o < 512; ++o) acc += hb[o] * w2[o * 8 + tid];
        pp[tid] = acc;
    }
    __syncthreads();
    if (tid < NW_) {
        float pa = pp[2 * tid], pb = pp[2 * tid + 1];
        float sp = fmaxf(pa, 0.f) + log1pf(expf(-fabsf(pa)));   // softplus
        dyn_a[b * NW_ + tid] = sp + 0.01f;
        dyn_b[b * NW_ + tid] = (1.f / (1.f + expf(-pb))) * (float)T_;
    }
}

// ---------------------------------------------------------------- K2b: psi[m][w] Ricker wavelet
__global__ __launch_bounds__(256) void psi_kernel(
    const float* __restrict__ dyn_a, const float* __restrict__ dyn_b,
    float* __restrict__ psi)
{
    int idx = blockIdx.x * 256 + threadIdx.x;   // M*NW = 65536
    int w = idx & 3, m = idx >> 2;
    int b = m >> 10, t = m & 1023;
    float z = ((float)t - dyn_b[b * 4 + w]) / dyn_a[b * 4 + w];
    float z2 = z * z;
    psi[idx] = (1.f - z2) * expf(-0.5f * z2);
}

// ---------------------------------------------------------------- GEMM: C[M][512] = A_virtual[M][K] * BT[512][K]^T
// MODE 0: A[m][c*4+d] = cheb_basis_d(xt[m][c])        (K=2048)
// MODE 1: A[m][w*512+c] = psi[m][w]*sctx[m][c]        (K=2048)
// MODE 2: A[m][k] = Aact[m][k]                        (K=512)
template<int MODE>
__global__ __launch_bounds__(256) void gemm_kernel(
    const bf16* __restrict__ Aact,   // [M][512]
    const bf16* __restrict__ BTm,    // [512][K]
    const float* __restrict__ psi,   // [M][4] (MODE 1)
    bf16* __restrict__ Cmat,         // [M][512]
    int K)
{
    constexpr int LD = 72;           // padded row stride (bf16 elems), 144B
    __shared__ bf16 lA[128 * LD];
    __shared__ bf16 lB[128 * LD];

    const int tid = threadIdx.x;
    const int m0 = blockIdx.y * 128, n0 = blockIdx.x * 128;
    const int row = tid >> 1, h = tid & 1;          // staging: 2 threads per row
    const int lane = tid & 63, wv = tid >> 6;
    const int wr = wv >> 1, wc = wv & 1;            // 2x2 waves of 64x64
    const int r16 = lane & 15, g = lane >> 4;

    f4v acc[4][4];
    #pragma unroll
    for (int i = 0; i < 4; ++i)
        #pragma unroll
        for (int j = 0; j < 4; ++j) acc[i][j] = (f4v)0.f;

    const int nK = K >> 6;
    for (int kt = 0; kt < nK; ++kt) {
        const int k0 = kt << 6;

        // ---- stage A tile [128][64] ----
        bf16* dstA = &lA[row * LD + h * 32];
        if (MODE == 0) {
            const int cb = (k0 >> 2) + h * 8;           // 8 xt values -> 32 basis values
            const bf16* src = Aact + (size_t)(m0 + row) * C_ + cb;
            bf16 tmp[8];
            *(s8v*)tmp = *(const s8v*)src;
            bf16 outv[32];
            #pragma unroll
            for (int cc = 0; cc < 8; ++cc) {
                float v = b2f(tmp[cc]);
                float v2 = v * v;
                outv[cc * 4 + 0] = f2b(1.f);
                outv[cc * 4 + 1] = tmp[cc];
                outv[cc * 4 + 2] = f2b(2.f * v2 - 1.f);
                outv[cc * 4 + 3] = f2b(v * (4.f * v2 - 3.f));
            }
            #pragma unroll
            for (int q = 0; q < 4; ++q) *(s8v*)&dstA[q * 8] = *(s8v*)&outv[q * 8];
        } else if (MODE == 1) {
            const int w  = k0 >> 9;
            const int cb = (k0 & 511) + h * 32;
            const bf16* src = Aact + (size_t)(m0 + row) * C_ + cb;
            const float ps = psi[(size_t)(m0 + row) * 4 + w];
            #pragma unroll
            for (int q = 0; q < 4; ++q) {
                bf16 tmp[8];
                *(s8v*)tmp = *(const s8v*)(src + q * 8);
                bf16 outv[8];
                #pragma unroll
                for (int e = 0; e < 8; ++e) outv[e] = f2b(b2f(tmp[e]) * ps);
                *(s8v*)&dstA[q * 8] = *(s8v*)outv;
            }
        } else {
            const bf16* src = Aact + (size_t)(m0 + row) * 512 + k0 + h * 32;
            #pragma unroll
            for (int q = 0; q < 4; ++q) *(s8v*)&dstA[q * 8] = *(const s8v*)(src + q * 8);
        }
        // ---- stage B tile [128 n][64 k] from BT[n][k] ----
        {
            const bf16* src = BTm + (size_t)(n0 + row) * K + k0 + h * 32;
            bf16* dstB = &lB[row * LD + h * 32];
            #pragma unroll
            for (int q = 0; q < 4; ++q) *(s8v*)&dstB[q * 8] = *(const s8v*)(src + q * 8);
        }
        __syncthreads();

        // ---- compute: 2 mfma-K steps of 32 ----
        #pragma unroll
        for (int ks = 0; ks < 2; ++ks) {
            s8v a[4], b[4];
            #pragma unroll
            for (int i = 0; i < 4; ++i)
                a[i] = *(const s8v*)&lA[(wr * 64 + i * 16 + r16) * LD + ks * 32 + g * 8];
            #pragma unroll
            for (int j = 0; j < 4; ++j)
                b[j] = *(const s8v*)&lB[(wc * 64 + j * 16 + r16) * LD + ks * 32 + g * 8];
            #pragma unroll
            for (int i = 0; i < 4; ++i)
                #pragma unroll
                for (int j = 0; j < 4; ++j)
                    acc[i][j] = __builtin_amdgcn_mfma_f32_16x16x32_bf16(a[i], b[j], acc[i][j], 0, 0, 0);
        }
        __syncthreads();
    }

    // ---- write C (D layout: col=lane&15, row=(lane>>4)*4+r) ----
    #pragma unroll
    for (int i = 0; i < 4; ++i)
        #pragma unroll
        for (int j = 0; j < 4; ++j)
            #pragma unroll
            for (int r = 0; r < 4; ++r) {
                int rr = m0 + wr * 64 + i * 16 + g * 4 + r;
                int cc = n0 + wc * 64 + j * 16 + r16;
                Cmat[(size_t)rr * 512 + cc] = f2b(acc[i][j][r]);
            }
}

// ---------------------------------------------------------------- K6: amp gate + residual + LayerNorm (f32 out)
__global__ __launch_bounds__(256) void epilogue_kernel(
    const float* __restrict__ x,   const bf16* __restrict__ tout,
    const bf16* __restrict__ sout, const bf16* __restrict__ ampin,
    const float* __restrict__ ampb, const float* __restrict__ gamma,
    const float* __restrict__ beta, float* __restrict__ out)
{
    __shared__ float red[8];
    const int m = blockIdx.x, tid = threadIdx.x;
    const size_t base = (size_t)m * 512;

    float y[2];
    #pragma unroll
    for (int q = 0; q < 2; ++q) {
        int c = tid + q * 256;
        float to = b2f(tout[base + c]);
        float so = b2f(sout[base + c]);
        float ai = b2f(ampin[base + c]) + ampb[c];
        float amp = 2.f / (1.f + expf(-ai));
        y[q] = to + so * amp + x[base + c];
    }
    float s = y[0] + y[1], sq = y[0] * y[0] + y[1] * y[1];
    #pragma unroll
    for (int off = 32; off >= 1; off >>= 1) {
        s  += __shfl_down(s, off);
        sq += __shfl_down(sq, off);
    }
    int lane = tid & 63, wv = tid >> 6;
    if (lane == 0) { red[wv * 2] = s; red[wv * 2 + 1] = sq; }
    __syncthreads();
    if (tid == 0) {
        float ts = 0.f, tq = 0.f;
        #pragma unroll
        for (int i = 0; i < 4; ++i) { ts += red[i * 2]; tq += red[i * 2 + 1]; }
        red[0] = ts; red[1] = tq;
    }
    __syncthreads();
    float mu  = red[0] * (1.f / 512.f);
    float var = red[1] * (1.f / 512.f) - mu * mu;
    float rstd = rsqrtf(var + 1e-5f);
    #pragma unroll
    for (int q = 0; q < 2; ++q) {
        int c = tid + q * 256;
        out[base + c] = (y[q] - mu) * rstd * gamma[c] + beta[c];
    }
}

// ----------------------------------------------------------------
extern "C" void kernel_launch(void* const* d_in, const int* in_sizes, int n_in,
                              void* d_out, int out_size, void* d_ws, size_t ws_size,
                              hipStream_t stream)
{
    const float* x     = (const float*)d_in[0];
    const float* tcw   = (const float*)d_in[1];
    const float* tcb   = (const float*)d_in[2];
    const float* scw   = (const float*)d_in[3];
    const float* scb   = (const float*)d_in[4];
    const float* lcw   = (const float*)d_in[5];
    const float* lcb   = (const float*)d_in[6];
    const float* cheby = (const float*)d_in[7];
    const float* hw1   = (const float*)d_in[8];
    const float* hb1   = (const float*)d_in[9];
    const float* hw2   = (const float*)d_in[10];
    const float* hb2   = (const float*)d_in[11];
    const float* ampw  = (const float*)d_in[12];
    const float* ampb  = (const float*)d_in[13];
    const float* wav   = (const float*)d_in[14];
    const float* lng   = (const float*)d_in[15];
    const float* lnb   = (const float*)d_in[16];
    float* out = (float*)d_out;

    char* ws = (char*)d_ws;
    size_t off = 0;
    auto alloc = [&](size_t bytes) -> char* {
        char* p = ws + off;
        off += (bytes + 255) & ~(size_t)255;
        return p;
    };
    bf16*  xt         = (bf16*)alloc((size_t)M_ * 512 * 2);
    bf16*  sctx       = (bf16*)alloc((size_t)M_ * 512 * 2);
    bf16*  tout       = (bf16*)alloc((size_t)M_ * 512 * 2);
    bf16*  sout       = (bf16*)alloc((size_t)M_ * 512 * 2);
    bf16*  ampin      = (bf16*)alloc((size_t)M_ * 512 * 2);
    bf16*  CCT        = (bf16*)alloc((size_t)512 * 2048 * 2);
    bf16*  WWT        = (bf16*)alloc((size_t)512 * 2048 * 2);
    bf16*  AWT        = (bf16*)alloc((size_t)512 * 512 * 2);
    float* slope_part = (float*)alloc(8 * B_ * C_ * 4);
    float* value_part = (float*)alloc(8 * B_ * C_ * 4);
    float* dyn_a      = (float*)alloc(B_ * NW_ * 4);
    float* dyn_b      = (float*)alloc(B_ * NW_ * 4);
    float* psi        = (float*)alloc((size_t)M_ * NW_ * 4);

    repack_kernel<<<4096, 256, 0, stream>>>(cheby, wav, ampw, CCT, WWT, AWT);
    decomp_kernel<<<dim3(2, 8, 16), 256, 0, stream>>>(x, tcw, tcb, scw, scb, lcw, lcb,
                                                      xt, sctx, slope_part, value_part);
    hyper_kernel<<<16, 256, 0, stream>>>(slope_part, value_part, hw1, hb1, hw2, hb2, dyn_a, dyn_b);
    psi_kernel<<<256, 256, 0, stream>>>(dyn_a, dyn_b, psi);
    gemm_kernel<0><<<dim3(4, 128), 256, 0, stream>>>(xt,   CCT, nullptr, tout,  2048);
    gemm_kernel<1><<<dim3(4, 128), 256, 0, stream>>>(sctx, WWT, psi,     sout,  2048);
    gemm_kernel<2><<<dim3(4, 128), 256, 0, stream>>>(tout, AWT, nullptr, ampin, 512);
    epilogue_kernel<<<16384, 256, 0, stream>>>(x, tout, sout, ampin, ampb, lng, lnb, out);
}

// Round 3
// 268.710 us; speedup vs baseline: 1.3514x; 1.3514x over previous
//
#include <hip/hip_runtime.h>
#include <hip/hip_bf16.h>
#include <math.h>

typedef __hip_bfloat16 bf16;
typedef __attribute__((ext_vector_type(8))) short s8v;   // 8 bf16 (4 VGPRs)
typedef __attribute__((ext_vector_type(4))) float f4v;

#define B_   16
#define T_   1024
#define C_   512
#define M_   (B_*T_)      // 16384
#define NW_  4
#define KWIN 25

__device__ __forceinline__ float b2f(bf16 v){ return __bfloat162float(v); }
__device__ __forceinline__ bf16  f2b(float v){ return __float2bfloat16(v); }

// ---------------------------------------------------------------- K0: repack f32 weights -> transposed bf16 panels
__global__ __launch_bounds__(256) void repack_kernel(
    const float* __restrict__ cheby,  // [C][C][4]  (c,o,d)
    const float* __restrict__ wav,    // [NW][C][C] (w,c,o)
    const float* __restrict__ ampw,   // [C][C]     (c,o)
    bf16* __restrict__ CCT,           // [512][2048] : CCT[o][c*4+d]
    bf16* __restrict__ WWT,           // [512][2048] : WWT[o][w*512+c]
    bf16* __restrict__ AWT)           // [512][512]  : AWT[o][c]
{
    int id = blockIdx.x * 256 + threadIdx.x;
    if (id < 512 * 2048) {
        int o = id >> 11, k = id & 2047;
        int c = k >> 2, d = k & 3;
        CCT[id] = f2b(cheby[c * 2048 + o * 4 + d]);
        int w = k >> 9, c2 = k & 511;
        WWT[id] = f2b(wav[(w * 512 + c2) * 512 + o]);
    }
    if (id < 512 * 512) {
        int o = id >> 9, c = id & 511;
        AWT[id] = f2b(ampw[c * 512 + o]);
    }
}

// ---------------------------------------------------------------- K0b: LDS-tiled transpose w1[1024][512] -> w1T[512][1024] (f32)
__global__ __launch_bounds__(256) void transpose_w1_kernel(
    const float* __restrict__ w1, float* __restrict__ w1t)
{
    __shared__ float tile[32][33];
    const int bo = blockIdx.x;          // 16 tiles along o
    const int bj = blockIdx.y;          // 32 tiles along j
    const int tx = threadIdx.x & 31, ty = threadIdx.x >> 5;   // 32x8
    #pragma unroll
    for (int r = 0; r < 32; r += 8)
        tile[ty + r][tx] = w1[(size_t)(bj * 32 + ty + r) * 512 + bo * 32 + tx];
    __syncthreads();
    #pragma unroll
    for (int r = 0; r < 32; r += 8)
        w1t[(size_t)(bo * 32 + ty + r) * 1024 + bj * 32 + tx] = tile[tx][ty + r];
}

// ---------------------------------------------------------------- K1: causal MA + dwconv3 x3 + pools, streaming over t
__global__ __launch_bounds__(256) void decomp_kernel(
    const float* __restrict__ x,
    const float* __restrict__ tcw, const float* __restrict__ tcb,
    const float* __restrict__ scw, const float* __restrict__ scb,
    const float* __restrict__ lcw, const float* __restrict__ lcb,
    bf16* __restrict__ xt,        // tanh(trend_ctx)  [M][C]
    bf16* __restrict__ sctx,      // spike_ctx        [M][C]
    float* __restrict__ slope_part,  // [8][B][C]
    float* __restrict__ value_part)  // [8][B][C]
{
    const int c     = blockIdx.x * 256 + threadIdx.x;  // gridDim.x = 2
    const int chunk = blockIdx.y;                      // 8 chunks of 128
    const int b     = blockIdx.z;
    const int t0    = chunk * 128;
    const float* xb = x + (size_t)b * T_ * C_ + c;

    auto X = [&](int i) -> float {
        i = i < 0 ? 0 : (i > T_ - 1 ? T_ - 1 : i);
        return xb[(size_t)i * C_];
    };

    const float w0t = tcw[c*3+0], w1t_ = tcw[c*3+1], w2t = tcw[c*3+2], bt0 = tcb[c];
    const float w0s = scw[c*3+0], w1s = scw[c*3+1], w2s = scw[c*3+2], bs0 = scb[c];
    const float w0l = lcw[c*3+0], w1l = lcw[c*3+1], w2l = lcw[c*3+2], bl0 = lcb[c];

    // init sliding window sum at j0 = max(t0-1, 0); window [j-24, j], K=25
    int j0 = (t0 > 0) ? (t0 - 1) : 0;
    float S = 0.f;
    #pragma unroll 1
    for (int i = j0 - (KWIN - 1); i <= j0; ++i) S += X(i);
    float trm = S * (1.f / KWIN), tr0;
    if (t0 > 0) { S += X(t0) - X(t0 - KWIN); tr0 = S * (1.f / KWIN); }
    else        { tr0 = trm; }
    float xm = X(t0 - 1), x0 = X(t0);

    float slopeAcc = 0.f, valAcc = 0.f;
    #pragma unroll 1
    for (int t = t0; t < t0 + 128; ++t) {
        float trp, xp;
        int tn = t + 1;
        if (tn <= T_ - 1) { S += X(tn) - X(tn - KWIN); trp = S * (1.f / KWIN); xp = X(tn); }
        else              { trp = tr0; xp = x0; }   // replicate pad at right edge

        float tctx  = w0t * trm + w1t_ * tr0 + w2t * trp + bt0;
        float sm = xm - trm, s0 = x0 - tr0, sp = xp - trp;
        float sctxv = w0s * sm + w1s * s0 + w2s * sp + bs0;
        float slp   = w0l * trm + w1l * tr0 + w2l * trp + bl0;
        slopeAcc += slp;
        valAcc   += tr0;

        size_t oidx = ((size_t)b * T_ + t) * C_ + c;
        xt[oidx]   = f2b(tanhf(tctx));
        sctx[oidx] = f2b(sctxv);

        trm = tr0; tr0 = trp; xm = x0; x0 = xp;
    }
    int pidx = (chunk * B_ + b) * C_ + c;
    slope_part[pidx] = slopeAcc;
    value_part[pidx] = valAcc;
}

// ---------------------------------------------------------------- K2a: pool reduce -> pc[16][1024]
__global__ __launch_bounds__(256) void pool_kernel(
    const float* __restrict__ slope_part, const float* __restrict__ value_part,
    float* __restrict__ pc)
{
    int idx = blockIdx.x * 256 + threadIdx.x;   // 16384
    int b = idx >> 10, j = idx & 1023;
    int c = j & 511;
    const float* src = (j < 512) ? slope_part : value_part;
    float s = 0.f;
    #pragma unroll
    for (int ch = 0; ch < 8; ++ch) s += src[(ch * B_ + b) * C_ + c];
    pc[idx] = s * (1.f / T_);
}

// ---------------------------------------------------------------- K2b: h[b][o] = silu(pc[b][:] . w1T[o][:] + b1[o]); 1 block per o
__global__ __launch_bounds__(256) void hyper1_kernel(
    const float* __restrict__ pc, const float* __restrict__ w1t,
    const float* __restrict__ b1, float* __restrict__ h)
{
    const int o = blockIdx.x, t = threadIdx.x;
    const float4 w = *(const float4*)&w1t[(size_t)o * 1024 + t * 4];
    float acc[16];
    #pragma unroll
    for (int b = 0; b < 16; ++b) {
        float4 p = *(const float4*)&pc[(size_t)b * 1024 + t * 4];
        acc[b] = w.x * p.x + w.y * p.y + w.z * p.z + w.w * p.w;
    }
    #pragma unroll
    for (int off = 32; off >= 1; off >>= 1)
        #pragma unroll
        for (int b = 0; b < 16; ++b) acc[b] += __shfl_down(acc[b], off);
    __shared__ float red[4][16];
    int lane = t & 63, wv = t >> 6;
    if (lane == 0)
        #pragma unroll
        for (int b = 0; b < 16; ++b) red[wv][b] = acc[b];
    __syncthreads();
    if (t < 16) {
        float s = red[0][t] + red[1][t] + red[2][t] + red[3][t] + b1[o];
        h[(size_t)t * 512 + o] = s / (1.f + expf(-s));   // silu
    }
}

// ---------------------------------------------------------------- K2c: params -> dyn_a, dyn_b (one block)
__global__ __launch_bounds__(128) void hyper2_kernel(
    const float* __restrict__ h, const float* __restrict__ w2,
    const float* __restrict__ b2, float* __restrict__ dyn_a, float* __restrict__ dyn_b)
{
    __shared__ float pp[16][8];
    const int t = threadIdx.x, b = t >> 3, o = t & 7;
    float acc = b2[o];
    #pragma unroll 4
    for (int j = 0; j < 512; ++j) acc += h[(size_t)b * 512 + j] * w2[j * 8 + o];
    pp[b][o] = acc;
    __syncthreads();
    if (t < 64) {
        int bb = t >> 2, w = t & 3;
        float pa = pp[bb][2 * w], pb = pp[bb][2 * w + 1];
        float sp = fmaxf(pa, 0.f) + log1pf(expf(-fabsf(pa)));   // softplus
        dyn_a[bb * NW_ + w] = sp + 0.01f;
        dyn_b[bb * NW_ + w] = (1.f / (1.f + expf(-pb))) * (float)T_;
    }
}

// ---------------------------------------------------------------- K2d: psi[m][w] Ricker wavelet
__global__ __launch_bounds__(256) void psi_kernel(
    const float* __restrict__ dyn_a, const float* __restrict__ dyn_b,
    float* __restrict__ psi)
{
    int idx = blockIdx.x * 256 + threadIdx.x;   // M*NW = 65536
    int w = idx & 3, m = idx >> 2;
    int b = m >> 10, t = m & 1023;
    float z = ((float)t - dyn_b[b * 4 + w]) / dyn_a[b * 4 + w];
    float z2 = z * z;
    psi[idx] = (1.f - z2) * expf(-0.5f * z2);
}

// ---------------------------------------------------------------- GEMM: C[M][512] = A_virtual[M][K] * BT[512][K]^T
// MODE 0: A[m][c*4+d] = cheb_basis_d(xt[m][c])        (K=2048)
// MODE 1: A[m][w*512+c] = psi[m][w]*sctx[m][c]        (K=2048)
// MODE 2: A[m][k] = Aact[m][k]                        (K=512)
template<int MODE>
__global__ __launch_bounds__(256) void gemm_kernel(
    const bf16* __restrict__ Aact,   // [M][512]
    const bf16* __restrict__ BTm,    // [512][K]
    const float* __restrict__ psi,   // [M][4] (MODE 1)
    bf16* __restrict__ Cmat,         // [M][512]
    int K)
{
    constexpr int LD = 72;           // padded row stride (bf16 elems), 144B
    __shared__ bf16 lA[128 * LD];
    __shared__ bf16 lB[128 * LD];

    const int tid = threadIdx.x;
    const int m0 = blockIdx.y * 128, n0 = blockIdx.x * 128;
    const int row = tid >> 1, h = tid & 1;          // staging: 2 threads per row
    const int lane = tid & 63, wv = tid >> 6;
    const int wr = wv >> 1, wc = wv & 1;            // 2x2 waves of 64x64
    const int r16 = lane & 15, g = lane >> 4;

    f4v acc[4][4];
    #pragma unroll
    for (int i = 0; i < 4; ++i)
        #pragma unroll
        for (int j = 0; j < 4; ++j) acc[i][j] = (f4v)0.f;

    const int nK = K >> 6;
    for (int kt = 0; kt < nK; ++kt) {
        const int k0 = kt << 6;

        // ---- stage A tile [128][64] ----
        bf16* dstA = &lA[row * LD + h * 32];
        if (MODE == 0) {
            const int cb = (k0 >> 2) + h * 8;           // 8 xt values -> 32 basis values
            const bf16* src = Aact + (size_t)(m0 + row) * C_ + cb;
            bf16 tmp[8];
            *(s8v*)tmp = *(const s8v*)src;
            bf16 outv[32];
            #pragma unroll
            for (int cc = 0; cc < 8; ++cc) {
                float v = b2f(tmp[cc]);
                float v2 = v * v;
                outv[cc * 4 + 0] = f2b(1.f);
                outv[cc * 4 + 1] = tmp[cc];
                outv[cc * 4 + 2] = f2b(2.f * v2 - 1.f);
                outv[cc * 4 + 3] = f2b(v * (4.f * v2 - 3.f));
            }
            #pragma unroll
            for (int q = 0; q < 4; ++q) *(s8v*)&dstA[q * 8] = *(s8v*)&outv[q * 8];
        } else if (MODE == 1) {
            const int w  = k0 >> 9;
            const int cb = (k0 & 511) + h * 32;
            const bf16* src = Aact + (size_t)(m0 + row) * C_ + cb;
            const float ps = psi[(size_t)(m0 + row) * 4 + w];
            #pragma unroll
            for (int q = 0; q < 4; ++q) {
                bf16 tmp[8];
                *(s8v*)tmp = *(const s8v*)(src + q * 8);
                bf16 outv[8];
                #pragma unroll
                for (int e = 0; e < 8; ++e) outv[e] = f2b(b2f(tmp[e]) * ps);
                *(s8v*)&dstA[q * 8] = *(s8v*)outv;
            }
        } else {
            const bf16* src = Aact + (size_t)(m0 + row) * 512 + k0 + h * 32;
            #pragma unroll
            for (int q = 0; q < 4; ++q) *(s8v*)&dstA[q * 8] = *(const s8v*)(src + q * 8);
        }
        // ---- stage B tile [128 n][64 k] from BT[n][k] ----
        {
            const bf16* src = BTm + (size_t)(n0 + row) * K + k0 + h * 32;
            bf16* dstB = &lB[row * LD + h * 32];
            #pragma unroll
            for (int q = 0; q < 4; ++q) *(s8v*)&dstB[q * 8] = *(const s8v*)(src + q * 8);
        }
        __syncthreads();

        // ---- compute: 2 mfma-K steps of 32 ----
        #pragma unroll
        for (int ks = 0; ks < 2; ++ks) {
            s8v a[4], b[4];
            #pragma unroll
            for (int i = 0; i < 4; ++i)
                a[i] = *(const s8v*)&lA[(wr * 64 + i * 16 + r16) * LD + ks * 32 + g * 8];
            #pragma unroll
            for (int j = 0; j < 4; ++j)
                b[j] = *(const s8v*)&lB[(wc * 64 + j * 16 + r16) * LD + ks * 32 + g * 8];
            #pragma unroll
            for (int i = 0; i < 4; ++i)
                #pragma unroll
                for (int j = 0; j < 4; ++j)
                    acc[i][j] = __builtin_amdgcn_mfma_f32_16x16x32_bf16(a[i], b[j], acc[i][j], 0, 0, 0);
        }
        __syncthreads();
    }

    // ---- write C (D layout: col=lane&15, row=(lane>>4)*4+r) ----
    #pragma unroll
    for (int i = 0; i < 4; ++i)
        #pragma unroll
        for (int j = 0; j < 4; ++j)
            #pragma unroll
            for (int r = 0; r < 4; ++r) {
                int rr = m0 + wr * 64 + i * 16 + g * 4 + r;
                int cc = n0 + wc * 64 + j * 16 + r16;
                Cmat[(size_t)rr * 512 + cc] = f2b(acc[i][j][r]);
            }
}

// ---------------------------------------------------------------- K6: amp gate + residual + LayerNorm (f32 out)
__global__ __launch_bounds__(256) void epilogue_kernel(
    const float* __restrict__ x,   const bf16* __restrict__ tout,
    const bf16* __restrict__ sout, const bf16* __restrict__ ampin,
    const float* __restrict__ ampb, const float* __restrict__ gamma,
    const float* __restrict__ beta, float* __restrict__ out)
{
    __shared__ float red[8];
    const int m = blockIdx.x, tid = threadIdx.x;
    const size_t base = (size_t)m * 512;

    float y[2];
    #pragma unroll
    for (int q = 0; q < 2; ++q) {
        int c = tid + q * 256;
        float to = b2f(tout[base + c]);
        float so = b2f(sout[base + c]);
        float ai = b2f(ampin[base + c]) + ampb[c];
        float amp = 2.f / (1.f + expf(-ai));
        y[q] = to + so * amp + x[base + c];
    }
    float s = y[0] + y[1], sq = y[0] * y[0] + y[1] * y[1];
    #pragma unroll
    for (int off = 32; off >= 1; off >>= 1) {
        s  += __shfl_down(s, off);
        sq += __shfl_down(sq, off);
    }
    int lane = tid & 63, wv = tid >> 6;
    if (lane == 0) { red[wv * 2] = s; red[wv * 2 + 1] = sq; }
    __syncthreads();
    if (tid == 0) {
        float ts = 0.f, tq = 0.f;
        #pragma unroll
        for (int i = 0; i < 4; ++i) { ts += red[i * 2]; tq += red[i * 2 + 1]; }
        red[0] = ts; red[1] = tq;
    }
    __syncthreads();
    float mu  = red[0] * (1.f / 512.f);
    float var = red[1] * (1.f / 512.f) - mu * mu;
    float rstd = rsqrtf(var + 1e-5f);
    #pragma unroll
    for (int q = 0; q < 2; ++q) {
        int c = tid + q * 256;
        out[base + c] = (y[q] - mu) * rstd * gamma[c] + beta[c];
    }
}

// ----------------------------------------------------------------
extern "C" void kernel_launch(void* const* d_in, const int* in_sizes, int n_in,
                              void* d_out, int out_size, void* d_ws, size_t ws_size,
                              hipStream_t stream)
{
    const float* x     = (const float*)d_in[0];
    const float* tcw   = (const float*)d_in[1];
    const float* tcb   = (const float*)d_in[2];
    const float* scw   = (const float*)d_in[3];
    const float* scb   = (const float*)d_in[4];
    const float* lcw   = (const float*)d_in[5];
    const float* lcb   = (const float*)d_in[6];
    const float* cheby = (const float*)d_in[7];
    const float* hw1   = (const float*)d_in[8];
    const float* hb1   = (const float*)d_in[9];
    const float* hw2   = (const float*)d_in[10];
    const float* hb2   = (const float*)d_in[11];
    const float* ampw  = (const float*)d_in[12];
    const float* ampb  = (const float*)d_in[13];
    const float* wav   = (const float*)d_in[14];
    const float* lng   = (const float*)d_in[15];
    const float* lnb   = (const float*)d_in[16];
    float* out = (float*)d_out;

    char* ws = (char*)d_ws;
    size_t off = 0;
    auto alloc = [&](size_t bytes) -> char* {
        char* p = ws + off;
        off += (bytes + 255) & ~(size_t)255;
        return p;
    };
    bf16*  xt         = (bf16*)alloc((size_t)M_ * 512 * 2);
    bf16*  sctx       = (bf16*)alloc((size_t)M_ * 512 * 2);
    bf16*  tout       = (bf16*)alloc((size_t)M_ * 512 * 2);
    bf16*  sout       = (bf16*)alloc((size_t)M_ * 512 * 2);
    bf16*  ampin      = (bf16*)alloc((size_t)M_ * 512 * 2);
    bf16*  CCT        = (bf16*)alloc((size_t)512 * 2048 * 2);
    bf16*  WWT        = (bf16*)alloc((size_t)512 * 2048 * 2);
    bf16*  AWT        = (bf16*)alloc((size_t)512 * 512 * 2);
    float* W1T        = (float*)alloc((size_t)512 * 1024 * 4);
    float* slope_part = (float*)alloc(8 * B_ * C_ * 4);
    float* value_part = (float*)alloc(8 * B_ * C_ * 4);
    float* pc         = (float*)alloc(B_ * 1024 * 4);
    float* hbuf       = (float*)alloc(B_ * C_ * 4);
    float* dyn_a      = (float*)alloc(B_ * NW_ * 4);
    float* dyn_b      = (float*)alloc(B_ * NW_ * 4);
    float* psi        = (float*)alloc((size_t)M_ * NW_ * 4);

    repack_kernel<<<4096, 256, 0, stream>>>(cheby, wav, ampw, CCT, WWT, AWT);
    transpose_w1_kernel<<<dim3(16, 32), 256, 0, stream>>>(hw1, W1T);
    decomp_kernel<<<dim3(2, 8, 16), 256, 0, stream>>>(x, tcw, tcb, scw, scb, lcw, lcb,
                                                      xt, sctx, slope_part, value_part);
    pool_kernel<<<64, 256, 0, stream>>>(slope_part, value_part, pc);
    hyper1_kernel<<<512, 256, 0, stream>>>(pc, W1T, hb1, hbuf);
    hyper2_kernel<<<1, 128, 0, stream>>>(hbuf, hw2, hb2, dyn_a, dyn_b);
    psi_kernel<<<256, 256, 0, stream>>>(dyn_a, dyn_b, psi);
    gemm_kernel<0><<<dim3(4, 128), 256, 0, stream>>>(xt,   CCT, nullptr, tout,  2048);
    gemm_kernel<1><<<dim3(4, 128), 256, 0, stream>>>(sctx, WWT, psi,     sout,  2048);
    gemm_kernel<2><<<dim3(4, 128), 256, 0, stream>>>(tout, AWT, nullptr, ampin, 512);
    epilogue_kernel<<<16384, 256, 0, stream>>>(x, tout, sout, ampin, ampb, lng, lnb, out);
}

// Round 4
// 255.583 us; speedup vs baseline: 1.4208x; 1.0514x over previous
//
#include <hip/hip_runtime.h>
#include <hip/hip_bf16.h>
#include <math.h>

typedef __hip_bfloat16 bf16;
typedef __attribute__((ext_vector_type(8))) short s8v;   // 8 bf16 (4 VGPRs)
typedef __attribute__((ext_vector_type(4))) float f4v;

#define B_   16
#define T_   1024
#define C_   512
#define M_   (B_*T_)      // 16384
#define NW_  4
#define KWIN 25
#define TCHUNK 16         // timesteps per thread (latency-hiding: 2048 blocks)

__device__ __forceinline__ float b2f(bf16 v){ return __bfloat162float(v); }
__device__ __forceinline__ bf16  f2b(float v){ return __float2bfloat16(v); }

// ---------------------------------------------------------------- K0: repack f32 weights -> transposed bf16 panels
__global__ __launch_bounds__(256) void repack_kernel(
    const float* __restrict__ cheby,  // [C][C][4]  (c,o,d)
    const float* __restrict__ wav,    // [NW][C][C] (w,c,o)
    const float* __restrict__ ampw,   // [C][C]     (c,o)
    bf16* __restrict__ CCT,           // [512][2048] : CCT[o][c*4+d]
    bf16* __restrict__ WWT,           // [512][2048] : WWT[o][w*512+c]
    bf16* __restrict__ AWT)           // [512][512]  : AWT[o][c]
{
    int id = blockIdx.x * 256 + threadIdx.x;
    if (id < 512 * 2048) {
        int o = id >> 11, k = id & 2047;
        int c = k >> 2, d = k & 3;
        CCT[id] = f2b(cheby[c * 2048 + o * 4 + d]);
        int w = k >> 9, c2 = k & 511;
        WWT[id] = f2b(wav[(w * 512 + c2) * 512 + o]);
    }
    if (id < 512 * 512) {
        int o = id >> 9, c = id & 511;
        AWT[id] = f2b(ampw[c * 512 + o]);
    }
}

// ---------------------------------------------------------------- K0b: LDS-tiled transpose w1[1024][512] -> w1T[512][1024] (f32)
__global__ __launch_bounds__(256) void transpose_w1_kernel(
    const float* __restrict__ w1, float* __restrict__ w1t)
{
    __shared__ float tile[32][33];
    const int bo = blockIdx.x;          // 16 tiles along o
    const int bj = blockIdx.y;          // 32 tiles along j
    const int tx = threadIdx.x & 31, ty = threadIdx.x >> 5;   // 32x8
    #pragma unroll
    for (int r = 0; r < 32; r += 8)
        tile[ty + r][tx] = w1[(size_t)(bj * 32 + ty + r) * 512 + bo * 32 + tx];
    __syncthreads();
    #pragma unroll
    for (int r = 0; r < 32; r += 8)
        w1t[(size_t)(bo * 32 + ty + r) * 1024 + bj * 32 + tx] = tile[tx][ty + r];
}

// ---------------------------------------------------------------- K1: causal MA + dwconv3 x3 + pools
// One thread = (b, c, chunk of TCHUNK timesteps). 2048 blocks -> 32 waves/CU.
__global__ __launch_bounds__(256) void decomp_kernel(
    const float* __restrict__ x,
    const float* __restrict__ tcw, const float* __restrict__ tcb,
    const float* __restrict__ scw, const float* __restrict__ scb,
    const float* __restrict__ lcw, const float* __restrict__ lcb,
    bf16* __restrict__ xt,        // tanh(trend_ctx)  [M][C]
    bf16* __restrict__ sctx,      // spike_ctx        [M][C]
    float* __restrict__ slope_part,  // [NCHUNK][B][C]
    float* __restrict__ value_part)  // [NCHUNK][B][C]
{
    const int c     = blockIdx.x * 256 + threadIdx.x;  // gridDim.x = 2
    const int chunk = blockIdx.y;                      // T_/TCHUNK chunks
    const int b     = blockIdx.z;
    const int t0    = chunk * TCHUNK;
    const float* xb = x + (size_t)b * T_ * C_ + c;

    auto X = [&](int i) -> float {
        i = i < 0 ? 0 : (i > T_ - 1 ? T_ - 1 : i);
        return xb[(size_t)i * C_];
    };

    const float w0t = tcw[c*3+0], w1t_ = tcw[c*3+1], w2t = tcw[c*3+2], bt0 = tcb[c];
    const float w0s = scw[c*3+0], w1s = scw[c*3+1], w2s = scw[c*3+2], bs0 = scb[c];
    const float w0l = lcw[c*3+0], w1l = lcw[c*3+1], w2l = lcw[c*3+2], bl0 = lcb[c];

    // init sliding window sum at j0 = max(t0-1, 0); window [j-24, j], K=25
    int j0 = (t0 > 0) ? (t0 - 1) : 0;
    float S = 0.f;
    #pragma unroll
    for (int i = j0 - (KWIN - 1); i <= j0; ++i) S += X(i);
    float trm = S * (1.f / KWIN), tr0;
    if (t0 > 0) { S += X(t0) - X(t0 - KWIN); tr0 = S * (1.f / KWIN); }
    else        { tr0 = trm; }
    float xm = X(t0 - 1), x0 = X(t0);

    float slopeAcc = 0.f, valAcc = 0.f;
    #pragma unroll
    for (int t = t0; t < t0 + TCHUNK; ++t) {
        float trp, xp;
        int tn = t + 1;
        if (tn <= T_ - 1) { S += X(tn) - X(tn - KWIN); trp = S * (1.f / KWIN); xp = X(tn); }
        else              { trp = tr0; xp = x0; }   // replicate pad at right edge

        float tctx  = w0t * trm + w1t_ * tr0 + w2t * trp + bt0;
        float sm = xm - trm, s0 = x0 - tr0, sp = xp - trp;
        float sctxv = w0s * sm + w1s * s0 + w2s * sp + bs0;
        float slp   = w0l * trm + w1l * tr0 + w2l * trp + bl0;
        slopeAcc += slp;
        valAcc   += tr0;

        size_t oidx = ((size_t)b * T_ + t) * C_ + c;
        xt[oidx]   = f2b(tanhf(tctx));
        sctx[oidx] = f2b(sctxv);

        trm = tr0; tr0 = trp; xm = x0; x0 = xp;
    }
    int pidx = (chunk * B_ + b) * C_ + c;
    slope_part[pidx] = slopeAcc;
    value_part[pidx] = valAcc;
}

// ---------------------------------------------------------------- K2a: pool reduce -> pc[16][1024]
__global__ __launch_bounds__(256) void pool_kernel(
    const float* __restrict__ slope_part, const float* __restrict__ value_part,
    float* __restrict__ pc)
{
    int idx = blockIdx.x * 256 + threadIdx.x;   // 16384
    int b = idx >> 10, j = idx & 1023;
    int c = j & 511;
    const float* src = (j < 512) ? slope_part : value_part;
    float s = 0.f;
    #pragma unroll
    for (int ch = 0; ch < (T_ / TCHUNK); ++ch) s += src[(ch * B_ + b) * C_ + c];
    pc[idx] = s * (1.f / T_);
}

// ---------------------------------------------------------------- K2b: h[b][o] = silu(pc[b][:] . w1T[o][:] + b1[o]); 1 block per o
__global__ __launch_bounds__(256) void hyper1_kernel(
    const float* __restrict__ pc, const float* __restrict__ w1t,
    const float* __restrict__ b1, float* __restrict__ h)
{
    const int o = blockIdx.x, t = threadIdx.x;
    const float4 w = *(const float4*)&w1t[(size_t)o * 1024 + t * 4];
    float acc[16];
    #pragma unroll
    for (int b = 0; b < 16; ++b) {
        float4 p = *(const float4*)&pc[(size_t)b * 1024 + t * 4];
        acc[b] = w.x * p.x + w.y * p.y + w.z * p.z + w.w * p.w;
    }
    #pragma unroll
    for (int off = 32; off >= 1; off >>= 1)
        #pragma unroll
        for (int b = 0; b < 16; ++b) acc[b] += __shfl_down(acc[b], off);
    __shared__ float red[4][16];
    int lane = t & 63, wv = t >> 6;
    if (lane == 0)
        #pragma unroll
        for (int b = 0; b < 16; ++b) red[wv][b] = acc[b];
    __syncthreads();
    if (t < 16) {
        float s = red[0][t] + red[1][t] + red[2][t] + red[3][t] + b1[o];
        h[(size_t)t * 512 + o] = s / (1.f + expf(-s));   // silu
    }
}

// ---------------------------------------------------------------- K2c: params -> dyn_a, dyn_b (one block)
__global__ __launch_bounds__(128) void hyper2_kernel(
    const float* __restrict__ h, const float* __restrict__ w2,
    const float* __restrict__ b2, float* __restrict__ dyn_a, float* __restrict__ dyn_b)
{
    __shared__ float pp[16][8];
    const int t = threadIdx.x, b = t >> 3, o = t & 7;
    float acc = b2[o];
    #pragma unroll 4
    for (int j = 0; j < 512; ++j) acc += h[(size_t)b * 512 + j] * w2[j * 8 + o];
    pp[b][o] = acc;
    __syncthreads();
    if (t < 64) {
        int bb = t >> 2, w = t & 3;
        float pa = pp[bb][2 * w], pb = pp[bb][2 * w + 1];
        float sp = fmaxf(pa, 0.f) + log1pf(expf(-fabsf(pa)));   // softplus
        dyn_a[bb * NW_ + w] = sp + 0.01f;
        dyn_b[bb * NW_ + w] = (1.f / (1.f + expf(-pb))) * (float)T_;
    }
}

// ---------------------------------------------------------------- K2d: psi[m][w] Ricker wavelet
__global__ __launch_bounds__(256) void psi_kernel(
    const float* __restrict__ dyn_a, const float* __restrict__ dyn_b,
    float* __restrict__ psi)
{
    int idx = blockIdx.x * 256 + threadIdx.x;   // M*NW = 65536
    int w = idx & 3, m = idx >> 2;
    int b = m >> 10, t = m & 1023;
    float z = ((float)t - dyn_b[b * 4 + w]) / dyn_a[b * 4 + w];
    float z2 = z * z;
    psi[idx] = (1.f - z2) * expf(-0.5f * z2);
}

// ---------------------------------------------------------------- GEMM: C[M][512] = A_virtual[M][K] * BT[512][K]^T
// MODE 0: A[m][c*4+d] = cheb_basis_d(xt[m][c])        (K=2048)
// MODE 1: A[m][w*512+c] = psi[m][w]*sctx[m][c]        (K=2048)
// MODE 2: A[m][k] = Aact[m][k]                        (K=512)
template<int MODE>
__global__ __launch_bounds__(256) void gemm_kernel(
    const bf16* __restrict__ Aact,   // [M][512]
    const bf16* __restrict__ BTm,    // [512][K]
    const float* __restrict__ psi,   // [M][4] (MODE 1)
    bf16* __restrict__ Cmat,         // [M][512]
    int K)
{
    constexpr int LD = 72;           // padded row stride (bf16 elems), 144B
    __shared__ bf16 lA[128 * LD];
    __shared__ bf16 lB[128 * LD];

    const int tid = threadIdx.x;
    const int m0 = blockIdx.y * 128, n0 = blockIdx.x * 128;
    const int row = tid >> 1, h = tid & 1;          // staging: 2 threads per row
    const int lane = tid & 63, wv = tid >> 6;
    const int wr = wv >> 1, wc = wv & 1;            // 2x2 waves of 64x64
    const int r16 = lane & 15, g = lane >> 4;

    f4v acc[4][4];
    #pragma unroll
    for (int i = 0; i < 4; ++i)
        #pragma unroll
        for (int j = 0; j < 4; ++j) acc[i][j] = (f4v)0.f;

    const int nK = K >> 6;
    for (int kt = 0; kt < nK; ++kt) {
        const int k0 = kt << 6;

        // ---- stage A tile [128][64] ----
        bf16* dstA = &lA[row * LD + h * 32];
        if (MODE == 0) {
            const int cb = (k0 >> 2) + h * 8;           // 8 xt values -> 32 basis values
            const bf16* src = Aact + (size_t)(m0 + row) * C_ + cb;
            bf16 tmp[8];
            *(s8v*)tmp = *(const s8v*)src;
            bf16 outv[32];
            #pragma unroll
            for (int cc = 0; cc < 8; ++cc) {
                float v = b2f(tmp[cc]);
                float v2 = v * v;
                outv[cc * 4 + 0] = f2b(1.f);
                outv[cc * 4 + 1] = tmp[cc];
                outv[cc * 4 + 2] = f2b(2.f * v2 - 1.f);
                outv[cc * 4 + 3] = f2b(v * (4.f * v2 - 3.f));
            }
            #pragma unroll
            for (int q = 0; q < 4; ++q) *(s8v*)&dstA[q * 8] = *(s8v*)&outv[q * 8];
        } else if (MODE == 1) {
            const int w  = k0 >> 9;
            const int cb = (k0 & 511) + h * 32;
            const bf16* src = Aact + (size_t)(m0 + row) * C_ + cb;
            const float ps = psi[(size_t)(m0 + row) * 4 + w];
            #pragma unroll
            for (int q = 0; q < 4; ++q) {
                bf16 tmp[8];
                *(s8v*)tmp = *(const s8v*)(src + q * 8);
                bf16 outv[8];
                #pragma unroll
                for (int e = 0; e < 8; ++e) outv[e] = f2b(b2f(tmp[e]) * ps);
                *(s8v*)&dstA[q * 8] = *(s8v*)outv;
            }
        } else {
            const bf16* src = Aact + (size_t)(m0 + row) * 512 + k0 + h * 32;
            #pragma unroll
            for (int q = 0; q < 4; ++q) *(s8v*)&dstA[q * 8] = *(const s8v*)(src + q * 8);
        }
        // ---- stage B tile [128 n][64 k] from BT[n][k] ----
        {
            const bf16* src = BTm + (size_t)(n0 + row) * K + k0 + h * 32;
            bf16* dstB = &lB[row * LD + h * 32];
            #pragma unroll
            for (int q = 0; q < 4; ++q) *(s8v*)&dstB[q * 8] = *(const s8v*)(src + q * 8);
        }
        __syncthreads();

        // ---- compute: 2 mfma-K steps of 32 ----
        #pragma unroll
        for (int ks = 0; ks < 2; ++ks) {
            s8v a[4], b[4];
            #pragma unroll
            for (int i = 0; i < 4; ++i)
                a[i] = *(const s8v*)&lA[(wr * 64 + i * 16 + r16) * LD + ks * 32 + g * 8];
            #pragma unroll
            for (int j = 0; j < 4; ++j)
                b[j] = *(const s8v*)&lB[(wc * 64 + j * 16 + r16) * LD + ks * 32 + g * 8];
            #pragma unroll
            for (int i = 0; i < 4; ++i)
                #pragma unroll
                for (int j = 0; j < 4; ++j)
                    acc[i][j] = __builtin_amdgcn_mfma_f32_16x16x32_bf16(a[i], b[j], acc[i][j], 0, 0, 0);
        }
        __syncthreads();
    }

    // ---- write C (D layout: col=lane&15, row=(lane>>4)*4+r) ----
    #pragma unroll
    for (int i = 0; i < 4; ++i)
        #pragma unroll
        for (int j = 0; j < 4; ++j)
            #pragma unroll
            for (int r = 0; r < 4; ++r) {
                int rr = m0 + wr * 64 + i * 16 + g * 4 + r;
                int cc = n0 + wc * 64 + j * 16 + r16;
                Cmat[(size_t)rr * 512 + cc] = f2b(acc[i][j][r]);
            }
}

// ---------------------------------------------------------------- K6: amp gate + residual + LayerNorm (f32 out)
__global__ __launch_bounds__(256) void epilogue_kernel(
    const float* __restrict__ x,   const bf16* __restrict__ tout,
    const bf16* __restrict__ sout, const bf16* __restrict__ ampin,
    const float* __restrict__ ampb, const float* __restrict__ gamma,
    const float* __restrict__ beta, float* __restrict__ out)
{
    __shared__ float red[8];
    const int m = blockIdx.x, tid = threadIdx.x;
    const size_t base = (size_t)m * 512;

    float y[2];
    #pragma unroll
    for (int q = 0; q < 2; ++q) {
        int c = tid + q * 256;
        float to = b2f(tout[base + c]);
        float so = b2f(sout[base + c]);
        float ai = b2f(ampin[base + c]) + ampb[c];
        float amp = 2.f / (1.f + expf(-ai));
        y[q] = to + so * amp + x[base + c];
    }
    float s = y[0] + y[1], sq = y[0] * y[0] + y[1] * y[1];
    #pragma unroll
    for (int off = 32; off >= 1; off >>= 1) {
        s  += __shfl_down(s, off);
        sq += __shfl_down(sq, off);
    }
    int lane = tid & 63, wv = tid >> 6;
    if (lane == 0) { red[wv * 2] = s; red[wv * 2 + 1] = sq; }
    __syncthreads();
    if (tid == 0) {
        float ts = 0.f, tq = 0.f;
        #pragma unroll
        for (int i = 0; i < 4; ++i) { ts += red[i * 2]; tq += red[i * 2 + 1]; }
        red[0] = ts; red[1] = tq;
    }
    __syncthreads();
    float mu  = red[0] * (1.f / 512.f);
    float var = red[1] * (1.f / 512.f) - mu * mu;
    float rstd = rsqrtf(var + 1e-5f);
    #pragma unroll
    for (int q = 0; q < 2; ++q) {
        int c = tid + q * 256;
        out[base + c] = (y[q] - mu) * rstd * gamma[c] + beta[c];
    }
}

// ----------------------------------------------------------------
extern "C" void kernel_launch(void* const* d_in, const int* in_sizes, int n_in,
                              void* d_out, int out_size, void* d_ws, size_t ws_size,
                              hipStream_t stream)
{
    const float* x     = (const float*)d_in[0];
    const float* tcw   = (const float*)d_in[1];
    const float* tcb   = (const float*)d_in[2];
    const float* scw   = (const float*)d_in[3];
    const float* scb   = (const float*)d_in[4];
    const float* lcw   = (const float*)d_in[5];
    const float* lcb   = (const float*)d_in[6];
    const float* cheby = (const float*)d_in[7];
    const float* hw1   = (const float*)d_in[8];
    const float* hb1   = (const float*)d_in[9];
    const float* hw2   = (const float*)d_in[10];
    const float* hb2   = (const float*)d_in[11];
    const float* ampw  = (const float*)d_in[12];
    const float* ampb  = (const float*)d_in[13];
    const float* wav   = (const float*)d_in[14];
    const float* lng   = (const float*)d_in[15];
    const float* lnb   = (const float*)d_in[16];
    float* out = (float*)d_out;

    char* ws = (char*)d_ws;
    size_t off = 0;
    auto alloc = [&](size_t bytes) -> char* {
        char* p = ws + off;
        off += (bytes + 255) & ~(size_t)255;
        return p;
    };
    const int NCHUNK = T_ / TCHUNK;   // 64
    bf16*  xt         = (bf16*)alloc((size_t)M_ * 512 * 2);
    bf16*  sctx       = (bf16*)alloc((size_t)M_ * 512 * 2);
    bf16*  tout       = (bf16*)alloc((size_t)M_ * 512 * 2);
    bf16*  sout       = (bf16*)alloc((size_t)M_ * 512 * 2);
    bf16*  ampin      = (bf16*)alloc((size_t)M_ * 512 * 2);
    bf16*  CCT        = (bf16*)alloc((size_t)512 * 2048 * 2);
    bf16*  WWT        = (bf16*)alloc((size_t)512 * 2048 * 2);
    bf16*  AWT        = (bf16*)alloc((size_t)512 * 512 * 2);
    float* W1T        = (float*)alloc((size_t)512 * 1024 * 4);
    float* slope_part = (float*)alloc((size_t)NCHUNK * B_ * C_ * 4);
    float* value_part = (float*)alloc((size_t)NCHUNK * B_ * C_ * 4);
    float* pc         = (float*)alloc(B_ * 1024 * 4);
    float* hbuf       = (float*)alloc(B_ * C_ * 4);
    float* dyn_a      = (float*)alloc(B_ * NW_ * 4);
    float* dyn_b      = (float*)alloc(B_ * NW_ * 4);
    float* psi        = (float*)alloc((size_t)M_ * NW_ * 4);

    repack_kernel<<<4096, 256, 0, stream>>>(cheby, wav, ampw, CCT, WWT, AWT);
    transpose_w1_kernel<<<dim3(16, 32), 256, 0, stream>>>(hw1, W1T);
    decomp_kernel<<<dim3(2, NCHUNK, 16), 256, 0, stream>>>(x, tcw, tcb, scw, scb, lcw, lcb,
                                                           xt, sctx, slope_part, value_part);
    pool_kernel<<<64, 256, 0, stream>>>(slope_part, value_part, pc);
    hyper1_kernel<<<512, 256, 0, stream>>>(pc, W1T, hb1, hbuf);
    hyper2_kernel<<<1, 128, 0, stream>>>(hbuf, hw2, hb2, dyn_a, dyn_b);
    psi_kernel<<<256, 256, 0, stream>>>(dyn_a, dyn_b, psi);
    gemm_kernel<0><<<dim3(4, 128), 256, 0, stream>>>(xt,   CCT, nullptr, tout,  2048);
    gemm_kernel<1><<<dim3(4, 128), 256, 0, stream>>>(sctx, WWT, psi,     sout,  2048);
    gemm_kernel<2><<<dim3(4, 128), 256, 0, stream>>>(tout, AWT, nullptr, ampin, 512);
    epilogue_kernel<<<16384, 256, 0, stream>>>(x, tout, sout, ampin, ampb, lng, lnb, out);
}